// Round 1
// baseline (7785.783 us; speedup 1.0000x reference)
//
#include <hip/hip_runtime.h>

#define HIDDEN 32
#define FF 40
#define SEQ_T 512

// Baseline design: one thread per batch row (16384 rows -> 256 waves).
// - All weights are read via wave-uniform addresses -> compiler emits s_load
//   (SGPR operand of v_fmac_f32), so weights cost zero VGPRs per lane.
// - h / accumulators fully unrolled into registers (~140 VGPR peak).
// - Layer-1 loop is i-outer / j-inner so the 40 consecutive W1[i*40+j] scalar
//   loads merge into s_load_dwordx16 batches (3 loads per i per matrix).
// Known structural ceiling: 256 waves = 1/4 of SIMDs busy -> ~1.7 ms floor.
__global__ __launch_bounds__(64, 1) void rnn_fp32_kernel(
    const float* __restrict__ inputs,
    const float* __restrict__ W1hh, const float* __restrict__ b1hh,
    const float* __restrict__ W2hh, const float* __restrict__ b2hh,
    const float* __restrict__ W1ho, const float* __restrict__ b1ho,
    const float* __restrict__ W2ho, const float* __restrict__ b2ho,
    float* __restrict__ ys, int B)
{
    const int r = blockIdx.x * blockDim.x + threadIdx.x;
    if (r >= B) return;
    const float* __restrict__ in_row = inputs + (size_t)r * SEQ_T;
    float* __restrict__ out_row = ys + (size_t)r * SEQ_T;

    float h[HIDDEN];
#pragma unroll
    for (int i = 0; i < HIDDEN; ++i) h[i] = 0.0f;

    for (int t = 0; t < SEQ_T; ++t) {
        const float u = in_row[t];

        // ---- layer 1: a = c @ W1hh + b1hh ; b = c @ W1ho + b1ho ----
        float a[FF], bb[FF];
#pragma unroll
        for (int j = 0; j < FF; ++j) { a[j] = b1hh[j]; bb[j] = b1ho[j]; }
#pragma unroll
        for (int i = 0; i < HIDDEN; ++i) {
            const float hi = h[i];
#pragma unroll
            for (int j = 0; j < FF; ++j) {
                a[j]  = __builtin_fmaf(hi, W1hh[i * FF + j], a[j]);
                bb[j] = __builtin_fmaf(hi, W1ho[i * FF + j], bb[j]);
            }
        }
#pragma unroll
        for (int j = 0; j < FF; ++j) {
            a[j]  = __builtin_fmaf(u, W1hh[HIDDEN * FF + j], a[j]);
            bb[j] = __builtin_fmaf(u, W1ho[HIDDEN * FF + j], bb[j]);
        }

        // ---- sigmoid ----
#pragma unroll
        for (int j = 0; j < FF; ++j) {
            a[j]  = __builtin_amdgcn_rcpf(1.0f + __expf(-a[j]));
            bb[j] = __builtin_amdgcn_rcpf(1.0f + __expf(-bb[j]));
        }

        // ---- layer 2: hn = s_hh @ W2hh + b2hh ; o = s_ho @ W2ho + b2ho ----
        float o = b2ho[0];
        float hn[HIDDEN];
#pragma unroll
        for (int i = 0; i < HIDDEN; ++i) hn[i] = b2hh[i];
#pragma unroll
        for (int j = 0; j < FF; ++j) {
            o = __builtin_fmaf(bb[j], W2ho[j], o);
            const float sj = a[j];
#pragma unroll
            for (int i = 0; i < HIDDEN; ++i)
                hn[i] = __builtin_fmaf(sj, W2hh[j * HIDDEN + i], hn[i]);
        }
#pragma unroll
        for (int i = 0; i < HIDDEN; ++i) h[i] = hn[i];
        out_row[t] = o;
    }
}

extern "C" void kernel_launch(void* const* d_in, const int* in_sizes, int n_in,
                              void* d_out, int out_size, void* d_ws, size_t ws_size,
                              hipStream_t stream) {
    const float* inputs = (const float*)d_in[0];
    const float* W1hh   = (const float*)d_in[1];
    const float* b1hh   = (const float*)d_in[2];
    const float* W2hh   = (const float*)d_in[3];
    const float* b2hh   = (const float*)d_in[4];
    const float* W1ho   = (const float*)d_in[5];
    const float* b1ho   = (const float*)d_in[6];
    const float* W2ho   = (const float*)d_in[7];
    const float* b2ho   = (const float*)d_in[8];
    float* ys = (float*)d_out;

    const int B = in_sizes[0] / SEQ_T;   // 16384
    const int threads = 64;              // one wave per block -> spread over all 256 CUs
    const int blocks = (B + threads - 1) / threads;
    rnn_fp32_kernel<<<blocks, threads, 0, stream>>>(
        inputs, W1hh, b1hh, W2hh, b2hh, W1ho, b1ho, W2ho, b2ho, ys, B);
}

// Round 3
// 1964.683 us; speedup vs baseline: 3.9629x; 3.9629x over previous
//
#include <hip/hip_runtime.h>

#define HIDDEN 32
#define FF 40
#define SEQ_T 512
#define NW 4        // waves per block (FF split across waves)
#define SL 10       // FF columns per wave

// ws layout (floats):
//   A[40*40]   = W2hh @ W1hh[:32,:]   (fused recurrence matrix, hh path)
//   Bm[40*40]  = W2hh @ W1ho[:32,:]   (fused matrix, output path)
//   beta_hh[40], beta_ho[40]          (fused biases, t>=1)
//   wu_hh[40], wu_ho[40]              (input-row weights W1*[32,:])
#define WS_A  0
#define WS_B  1600
#define WS_BH 3200
#define WS_BO 3240
#define WS_UH 3280
#define WS_UO 3320

__global__ __launch_bounds__(256, 1) void rnn_prep(
    const float* __restrict__ W1hh, const float* __restrict__ b1hh,
    const float* __restrict__ W2hh, const float* __restrict__ b2hh,
    const float* __restrict__ W1ho, const float* __restrict__ b1ho,
    float* __restrict__ ws)
{
    const int t = threadIdx.x;
    for (int idx = t; idx < 1600; idx += 256) {
        const int j = idx / 40, jp = idx % 40;
        float a = 0.f, b = 0.f;
        for (int i = 0; i < HIDDEN; ++i) {
            const float w2 = W2hh[j * HIDDEN + i];
            a = __builtin_fmaf(w2, W1hh[i * FF + jp], a);
            b = __builtin_fmaf(w2, W1ho[i * FF + jp], b);
        }
        ws[WS_A + idx] = a;
        ws[WS_B + idx] = b;
    }
    if (t < FF) {
        float bh = b1hh[t], bo = b1ho[t];
        for (int i = 0; i < HIDDEN; ++i) {
            bh = __builtin_fmaf(b2hh[i], W1hh[i * FF + t], bh);
            bo = __builtin_fmaf(b2hh[i], W1ho[i * FF + t], bo);
        }
        ws[WS_BH + t] = bh;
        ws[WS_BO + t] = bo;
        ws[WS_UH + t] = W1hh[HIDDEN * FF + t];
        ws[WS_UO + t] = W1ho[HIDDEN * FF + t];
    }
}

__device__ __forceinline__ float sigmoid_fast(float x) {
    // 1/(1+exp(-x)); HW transcendental is 2^x, so exp(-x)=exp2(-x*log2(e))
    const float e = __builtin_amdgcn_exp2f(-x * 1.44269504088896341f);
    return __builtin_amdgcn_rcpf(1.0f + e);
}

// Block = 256 threads = 4 waves covering 64 rows (lane = row).
// Wave w owns FF columns [10w, 10w+10). Weights indexed wave-uniformly
// (readfirstlane) -> scalar loads, zero VGPR cost.
// Cross-step state: only s = sigmoid(z_hh) (40 floats/row), exchanged via
// double-buffered LDS [j][lane] (bank = lane%32, 2-way aliasing = free).
__global__ __launch_bounds__(256, 1) void rnn_main(
    const float* __restrict__ inputs,
    const float* __restrict__ ws,
    const float* __restrict__ b1hh, const float* __restrict__ b1ho,
    const float* __restrict__ W2ho, const float* __restrict__ b2ho,
    float* __restrict__ ys)
{
    const int lane = threadIdx.x & 63;
    const int w = __builtin_amdgcn_readfirstlane(threadIdx.x >> 6); // 0..3
    const int jb = w * SL;                                          // uniform
    const int r = blockIdx.x * 64 + lane;
    const float* __restrict__ in_row = inputs + (size_t)r * SEQ_T;
    float* __restrict__ out_row = ys + (size_t)r * SEQ_T;

    const float* __restrict__ A    = ws + WS_A;
    const float* __restrict__ Bm   = ws + WS_B;
    const float* __restrict__ bhh  = ws + WS_BH;
    const float* __restrict__ bho  = ws + WS_BO;
    const float* __restrict__ uhh  = ws + WS_UH;
    const float* __restrict__ uho  = ws + WS_UO;

    __shared__ float s_ex[2][FF][64];
    __shared__ float o_ex[2][NW][64];

    // ---- step 0: h(0)=0 -> z = u*wu + b1 (raw layer-1 bias) ----
    float u = in_row[0];
    {
        float z[SL], zo[SL], op = 0.f;
#pragma unroll
        for (int k = 0; k < SL; ++k) {
            z[k]  = __builtin_fmaf(u, uhh[jb + k], b1hh[jb + k]);
            zo[k] = __builtin_fmaf(u, uho[jb + k], b1ho[jb + k]);
            z[k]  = sigmoid_fast(z[k]);
            op = __builtin_fmaf(sigmoid_fast(zo[k]), W2ho[jb + k], op);
            s_ex[0][jb + k][lane] = z[k];
        }
        o_ex[0][w][lane] = op;
    }
    float un = in_row[1];
    __syncthreads();

    const float b2o = b2ho[0];

    for (int t = 1; t < SEQ_T; ++t) {
        const int rb = (t - 1) & 1;
        const int wb = t & 1;

        // gather full s(t-1): conflict-free b32 reads
        float sv[FF];
#pragma unroll
        for (int j = 0; j < FF; ++j) sv[j] = s_ex[rb][j][lane];

        // one wave (rotating) reduces o(t-1) and stores it
        if (w == ((t - 1) & 3)) {
            float o = o_ex[rb][0][lane] + o_ex[rb][1][lane]
                    + o_ex[rb][2][lane] + o_ex[rb][3][lane] + b2o;
            out_row[t - 1] = o;
        }

        u = un;
        float z[SL], zo[SL];
#pragma unroll
        for (int k = 0; k < SL; ++k) {
            z[k]  = __builtin_fmaf(u, uhh[jb + k], bhh[jb + k]);
            zo[k] = __builtin_fmaf(u, uho[jb + k], bho[jb + k]);
        }
#pragma unroll
        for (int j = 0; j < FF; ++j) {
            const float sj = sv[j];
#pragma unroll
            for (int k = 0; k < SL; ++k) {
                z[k]  = __builtin_fmaf(sj, A[j * FF + jb + k],  z[k]);
                zo[k] = __builtin_fmaf(sj, Bm[j * FF + jb + k], zo[k]);
            }
        }

        float op = 0.f;
#pragma unroll
        for (int k = 0; k < SL; ++k) {
            z[k] = sigmoid_fast(z[k]);                    // s(t) slice
            op = __builtin_fmaf(sigmoid_fast(zo[k]), W2ho[jb + k], op);
            s_ex[wb][jb + k][lane] = z[k];
        }
        o_ex[wb][w][lane] = op;

        un = in_row[t < SEQ_T - 1 ? t + 1 : SEQ_T - 1];   // prefetch next u
        __syncthreads();
    }

    // epilogue: o(511) lives in buffer (511 & 1) = 1
    if (w == ((SEQ_T - 1) & 3)) {
        float o = o_ex[1][0][lane] + o_ex[1][1][lane]
                + o_ex[1][2][lane] + o_ex[1][3][lane] + b2o;
        out_row[SEQ_T - 1] = o;
    }
}

extern "C" void kernel_launch(void* const* d_in, const int* in_sizes, int n_in,
                              void* d_out, int out_size, void* d_ws, size_t ws_size,
                              hipStream_t stream) {
    const float* inputs = (const float*)d_in[0];
    const float* W1hh   = (const float*)d_in[1];
    const float* b1hh   = (const float*)d_in[2];
    const float* W2hh   = (const float*)d_in[3];
    const float* b2hh   = (const float*)d_in[4];
    const float* W1ho   = (const float*)d_in[5];
    const float* b1ho   = (const float*)d_in[6];
    const float* W2ho   = (const float*)d_in[7];
    const float* b2ho   = (const float*)d_in[8];
    float* ys = (float*)d_out;
    float* ws = (float*)d_ws;

    const int B = in_sizes[0] / SEQ_T;   // 16384

    rnn_prep<<<1, 256, 0, stream>>>(W1hh, b1hh, W2hh, b2hh, W1ho, b1ho, ws);

    const int blocks = B / 64;           // 256 blocks of 4 waves
    rnn_main<<<blocks, 256, 0, stream>>>(inputs, ws, b1hh, b1ho, W2ho, b2ho, ys);
}